// Round 5
// baseline (50.002 us; speedup 1.0000x reference)
//
#include <hip/hip_runtime.h>

#define QN_F (-127.0f)
#define QP_F (127.0f)
#define MSB 128

typedef float f32x4 __attribute__((ext_vector_type(4)));

// Fused, grid-stride. Owner block of flat element e under grid-stride over
// float4 indices with power-of-two stride S=grid*block:
//   owner = ((e>>2) & (S-1)) >> log2(block)
// Each block applies its own flips after __syncthreads() (vmcnt drained
// before s_barrier -> main-phase store retired to this CU's L2 before the
// flip overwrite from the same block).
__global__ void __launch_bounds__(256)
quant_fused_kernel(const float* __restrict__ w,
                   const float* __restrict__ alpha,
                   const int* __restrict__ flip_idx,
                   float* __restrict__ out,
                   int n4, int nf) {
    const float a = fmaxf(alpha[0], 1e-4f);
    const int stride = gridDim.x * blockDim.x;       // float4 stride per pass
    const int idx = blockIdx.x * blockDim.x + threadIdx.x;

    const f32x4* __restrict__ w4 = (const f32x4*)w;
    f32x4* __restrict__ out4 = (f32x4*)out;

    // uniform full passes -> unrolled bodies have no per-iter bounds check,
    // compiler can batch the 4 loads
    const int nfull = n4 / stride;
    int k = 0;
    #pragma unroll 4
    for (; k < nfull; ++k) {
        const int i = idx + k * stride;
        f32x4 v = w4[i];
        f32x4 r;
        r.x = rintf(fminf(fmaxf(v.x / a, QN_F), QP_F)) * a;
        r.y = rintf(fminf(fmaxf(v.y / a, QN_F), QP_F)) * a;
        r.z = rintf(fminf(fmaxf(v.z / a, QN_F), QP_F)) * a;
        r.w = rintf(fminf(fmaxf(v.w / a, QN_F), QP_F)) * a;
        __builtin_nontemporal_store(r, &out4[i]);
    }
    { // tail (empty when stride divides n4)
        const int i = idx + k * stride;
        if (i < n4) {
            f32x4 v = w4[i];
            f32x4 r;
            r.x = rintf(fminf(fmaxf(v.x / a, QN_F), QP_F)) * a;
            r.y = rintf(fminf(fmaxf(v.y / a, QN_F), QP_F)) * a;
            r.z = rintf(fminf(fmaxf(v.z / a, QN_F), QP_F)) * a;
            r.w = rintf(fminf(fmaxf(v.w / a, QN_F), QP_F)) * a;
            __builtin_nontemporal_store(r, &out4[i]);
        }
    }

    __syncthreads();   // drain stores before flip overwrites

    // flip-scan: apply only flips owned by this block (power-of-two stride)
    const unsigned smask = (unsigned)stride - 1u;    // stride is 2^k
    for (int t = (int)threadIdx.x; t < nf; t += (int)blockDim.x) {
        const int e = flip_idx[t];
        const unsigned owner = (((unsigned)e >> 2) & smask) / blockDim.x;
        if (owner == blockIdx.x) {
            float q = fminf(fmaxf(w[e] / a, QN_F), QP_F);
            int qi = (int)q;   // trunc toward zero == astype(int32)
            qi ^= MSB;         // full-width int32 XOR == numpy bitwise_xor
            out[e] = (float)qi * a;   // round(int) == int, then * a
        }
    }
}

extern "C" void kernel_launch(void* const* d_in, const int* in_sizes, int n_in,
                              void* d_out, int out_size, void* d_ws, size_t ws_size,
                              hipStream_t stream) {
    const float* w = (const float*)d_in[0];
    const float* alpha = (const float*)d_in[1];
    const int* flip_idx = (const int*)d_in[2];   // harness passes integers as int32
    float* out = (float*)d_out;

    const int n = in_sizes[0];          // 33554432
    const int nf = in_sizes[2];         // 3356
    const int n4 = n / 4;               // 8388608 float4s

    const int block = 256;
    const int grid = 2048;              // stride = 524288 (2^19), 16 passes
    quant_fused_kernel<<<grid, block, 0, stream>>>(w, alpha, flip_idx, out, n4, nf);
}

// Round 6
// 48.070 us; speedup vs baseline: 1.0402x; 1.0402x over previous
//
#include <hip/hip_runtime.h>

#define QN_F (-127.0f)
#define QP_F (127.0f)
#define MSB 128

typedef float f32x4 __attribute__((ext_vector_type(4)));

// Streaming store: system-scope + non-temporal (sc0 sc1 nt) — write through /
// bypass L2 and MALL so the output stream does not evict the L3-resident
// weight between graph replays. No "memory" clobber: w/out don't alias, and we
// want the unrolled loads to stay batched ahead of the stores.
__device__ __forceinline__ void stream_store4(f32x4* p, f32x4 v) {
    asm volatile("global_store_dwordx4 %0, %1, off sc0 sc1 nt"
                 :: "v"(p), "v"(v));
}

__global__ void __launch_bounds__(256)
quant_main_kernel(const f32x4* __restrict__ w4,
                  const float* __restrict__ alpha,
                  f32x4* __restrict__ out4,
                  int n4) {
    const float a = fmaxf(alpha[0], 1e-4f);
    const int idx = blockIdx.x * blockDim.x + threadIdx.x;
    const int stride = gridDim.x * blockDim.x;
    #pragma unroll 4
    for (int i = idx; i < n4; i += stride) {
        f32x4 v = w4[i];
        f32x4 r;
        r.x = rintf(fminf(fmaxf(v.x / a, QN_F), QP_F)) * a;
        r.y = rintf(fminf(fmaxf(v.y / a, QN_F), QP_F)) * a;
        r.z = rintf(fminf(fmaxf(v.z / a, QN_F), QP_F)) * a;
        r.w = rintf(fminf(fmaxf(v.w / a, QN_F), QP_F)) * a;
        stream_store4(&out4[i], r);
    }
}

__global__ void flip_fixup_kernel(const float* __restrict__ w,
                                  const float* __restrict__ alpha,
                                  const int* __restrict__ flip_idx,
                                  float* __restrict__ out,
                                  int nf) {
    const float a = fmaxf(alpha[0], 1e-4f);
    int t = blockIdx.x * blockDim.x + threadIdx.x;
    if (t < nf) {
        int i = flip_idx[t];
        float q = fminf(fmaxf(w[i] / a, QN_F), QP_F);
        int qi = (int)q;      // trunc toward zero == astype(int32)
        qi ^= MSB;            // full-width int32 XOR == numpy bitwise_xor
        out[i] = (float)qi * a;   // round(int) == int, then * a
    }
}

extern "C" void kernel_launch(void* const* d_in, const int* in_sizes, int n_in,
                              void* d_out, int out_size, void* d_ws, size_t ws_size,
                              hipStream_t stream) {
    const float* w = (const float*)d_in[0];
    const float* alpha = (const float*)d_in[1];
    const int* flip_idx = (const int*)d_in[2];   // harness passes integers as int32
    float* out = (float*)d_out;

    const int n = in_sizes[0];          // 33554432
    const int nf = in_sizes[2];         // 3356
    const int n4 = n / 4;               // 8388608 float4s

    const int block = 256;
    int grid = (n4 + block - 1) / block;
    if (grid > 2048) grid = 2048;       // grid-stride, 16 passes
    quant_main_kernel<<<grid, block, 0, stream>>>(
        (const f32x4*)w, alpha, (f32x4*)out, n4);

    int fgrid = (nf + block - 1) / block;
    flip_fixup_kernel<<<fgrid, block, 0, stream>>>(w, alpha, flip_idx, out, nf);
}